// Round 1
// baseline (383.078 us; speedup 1.0000x reference)
//
#include <hip/hip_runtime.h>

#define H 128

typedef __attribute__((ext_vector_type(8))) short s16x8;
typedef __attribute__((ext_vector_type(4))) float f32x4;

__device__ __forceinline__ float bf2f(unsigned short u){
  unsigned x = ((unsigned)u) << 16;
  return __builtin_bit_cast(float, x);
}
__device__ __forceinline__ unsigned short f2bf(float f){
  unsigned u = __builtin_bit_cast(unsigned, f);
  u += 0x7fff + ((u >> 16) & 1);
  return (unsigned short)(u >> 16);
}

// ---- weight prep: W_big [512][384] bf16, W_msg bf16, bias_big f32[512] ----
__global__ void prep_kernel(const float* W_msg, const float* W_ih, const float* W_hh,
                            const float* b_ih, const float* b_hh,
                            unsigned short* Wmsgb, unsigned short* Wbig, float* biasb){
  int i = blockIdx.x*256 + threadIdx.x;
  const int NW = 512*384;
  if(i < NW){
    int r = i / 384, k = i % 384;
    float v;
    if(r < 384) v = (k < 256) ? W_ih[r*256 + k] : W_hh[r*128 + (k-256)];
    else        v = (k < 256) ? 0.f : W_hh[(256 + (r-384))*128 + (k-256)];
    Wbig[i] = f2bf(v);
  } else if(i < NW + 128*256){
    int j = i - NW;
    Wmsgb[j] = f2bf(W_msg[j]);
  } else if(i < NW + 128*256 + 512){
    int r = i - NW - 128*256;
    biasb[r] = (r < 384) ? (b_ih[r] + b_hh[r]) : b_hh[256 + (r-384)];
  }
}

// ---- convert x,h f32 -> bf16 ----
__global__ void convert_kernel(const float* x, const float* h,
                               unsigned short* xb, unsigned short* hb, int nv){
  int i = blockIdx.x*256 + threadIdx.x;
  const float* sp; unsigned short* dp; int j;
  if(i < nv){ sp = x; dp = xb; j = i; }
  else if(i < 2*nv){ sp = h; dp = hb; j = i - nv; }
  else return;
  float4 v = ((const float4*)sp)[j];
  ushort4 o; o.x=f2bf(v.x); o.y=f2bf(v.y); o.z=f2bf(v.z); o.w=f2bf(v.w);
  ((ushort4*)dp)[j] = o;
}

// ---- CSR build ----
__global__ void hist_kernel(const int* dst, int* deg, int E){
  int e = blockIdx.x*256 + threadIdx.x;
  if(e < E) atomicAdd(&deg[dst[e]], 1);
}

__global__ void scan_kernel(const int* deg, int* rs, int* rc, int N, int CH){
  __shared__ int buf[1024];
  int t = threadIdx.x;
  int lo = t*CH, hi = min(lo+CH, N);
  int s = 0;
  for(int i=lo; i<hi; ++i) s += deg[i];
  buf[t] = s; __syncthreads();
  int own = s;
  for(int off=1; off<1024; off<<=1){
    int u = (t >= off) ? buf[t-off] : 0;
    __syncthreads();
    buf[t] += u;
    __syncthreads();
  }
  int run = buf[t] - own;   // exclusive prefix
  for(int i=lo; i<hi; ++i){ rs[i] = run; rc[i] = run; run += deg[i]; }
  if(t == 1023) rs[N] = buf[1023];
}

__global__ void fill_kernel(const int* src, const int* dst, int* rc, int* ss, int E){
  int e = blockIdx.x*256 + threadIdx.x;
  if(e < E){ int p = atomicAdd(&rc[dst[e]], 1); ss[p] = src[e]; }
}

// ---- aggregation: one wave per node, mean of concat(xb[src], hb[src]) -> Sb bf16 [N][256] ----
__global__ void agg_kernel(const unsigned short* xb, const unsigned short* hb,
                           const int* rs, const int* ss, unsigned short* Sb, int N){
  int wv = threadIdx.x >> 6, lane = threadIdx.x & 63;
  int node = blockIdx.x*4 + wv;
  if(node >= N) return;
  int e0 = rs[node], e1 = rs[node+1];
  const unsigned short* base = (lane < 32) ? xb : hb;
  int co = (lane & 31)*4;
  float a0=0.f, a1=0.f, a2=0.f, a3=0.f;
  for(int e=e0; e<e1; ++e){
    int s = ss[e];  // same address across wave -> broadcast
    ushort4 v = *(const ushort4*)(base + (long)s*H + co);
    a0 += bf2f(v.x); a1 += bf2f(v.y); a2 += bf2f(v.z); a3 += bf2f(v.w);
  }
  float inv = (e1 > e0) ? 1.0f/(float)(e1 - e0) : 0.f;
  ushort4 o; o.x=f2bf(a0*inv); o.y=f2bf(a1*inv); o.z=f2bf(a2*inv); o.w=f2bf(a3*inv);
  *(ushort4*)(Sb + (long)node*256 + lane*4) = o;
}

// ---- NT GEMM: out[M][NC] bf16 = A[M][K] (segments of 128 along K) @ B[NC][K]^T + bias ----
// 128x128 tile, BK=64, 4 waves, 16x16x32 bf16 MFMA, XOR-swizzled LDS.
template<int K, int NC, bool MASK>
__global__ __launch_bounds__(256) void gemm_kernel(
    const unsigned short* A0, const unsigned short* A1, const unsigned short* A2,
    int st0, int st1, int st2,
    const unsigned short* B, const float* bias, const int* deg,
    unsigned short* out, int M){
  __shared__ __align__(16) unsigned short ldsA[128*64];
  __shared__ __align__(16) unsigned short ldsB[128*64];
  int tid = threadIdx.x;
  int lane = tid & 63, wv = tid >> 6;
  int wr = wv >> 1, wc = wv & 1;
  int l15 = lane & 15, l4 = lane >> 4;
  long rowbase = (long)blockIdx.x * 128;
  int colbase = blockIdx.y * 128;

  const f32x4 fz = {0.f, 0.f, 0.f, 0.f};
  f32x4 acc[4][4];
  #pragma unroll
  for(int m=0;m<4;++m)
    #pragma unroll
    for(int n=0;n<4;++n) acc[m][n] = fz;

  for(int kt=0; kt<K/64; ++kt){
    // stage 128x64 A-tile and B-tile: linear global reads, swizzled LDS writes
    #pragma unroll
    for(int it=0; it<4; ++it){
      int slot = it*256 + tid;         // 0..1023
      int row = slot >> 3, c = slot & 7;
      int cw = c ^ (row & 7);
      // A (segmented along K in 128-col pieces)
      int kg = kt*64 + c*8;
      int seg = kg >> 7, kin = kg & 127;
      const unsigned short* ap = (seg==0) ? A0 : ((seg==1) ? A1 : A2);
      int st = (seg==0) ? st0 : ((seg==1) ? st1 : st2);
      long gr = rowbase + row; if(gr > M-1) gr = M-1;
      s16x8 va = *(const s16x8*)(ap + gr*(long)st + kin);
      *(s16x8*)((char*)ldsA + row*128 + cw*16) = va;
      // B: [NC][K] row-major
      s16x8 vb = *(const s16x8*)(B + (long)(colbase + row)*K + kt*64 + c*8);
      *(s16x8*)((char*)ldsB + row*128 + cw*16) = vb;
    }
    __syncthreads();

    s16x8 af[4][2], bfr[4][2];
    #pragma unroll
    for(int m=0;m<4;++m){
      int row = wr*64 + m*16 + l15;
      #pragma unroll
      for(int kk=0;kk<2;++kk){
        int ch = kk*4 + l4;
        af[m][kk] = *(const s16x8*)((char*)ldsA + row*128 + ((ch ^ (row & 7))*16));
      }
    }
    #pragma unroll
    for(int n=0;n<4;++n){
      int row = wc*64 + n*16 + l15;
      #pragma unroll
      for(int kk=0;kk<2;++kk){
        int ch = kk*4 + l4;
        bfr[n][kk] = *(const s16x8*)((char*)ldsB + row*128 + ((ch ^ (row & 7))*16));
      }
    }
    #pragma unroll
    for(int kk=0;kk<2;++kk)
      #pragma unroll
      for(int m=0;m<4;++m)
        #pragma unroll
        for(int n=0;n<4;++n)
          acc[m][n] = __builtin_amdgcn_mfma_f32_16x16x32_bf16(af[m][kk], bfr[n][kk], acc[m][n], 0, 0, 0);
    __syncthreads();
  }

  // epilogue: C/D layout col=lane&15, row=(lane>>4)*4+reg
  float bv[4];
  #pragma unroll
  for(int n=0;n<4;++n) bv[n] = bias[colbase + wc*64 + n*16 + l15];
  #pragma unroll
  for(int m=0;m<4;++m){
    long r0 = rowbase + wr*64 + m*16 + l4*4;
    #pragma unroll
    for(int n=0;n<4;++n){
      int col = colbase + wc*64 + n*16 + l15;
      #pragma unroll
      for(int r=0;r<4;++r){
        long row = r0 + r;
        if(row < M){
          float v = acc[m][n][r] + bv[n];
          if(MASK) v = (deg[row] > 0) ? v : 0.f;
          out[row*(long)NC + col] = f2bf(v);
        }
      }
    }
  }
}

// ---- gates: r,z,n + output ----
__global__ void gates_kernel(const unsigned short* P, const float* h, float* out, int N){
  int gid = blockIdx.x*256 + threadIdx.x;
  int node = gid >> 5, q = gid & 31;
  if(node >= N) return;
  const unsigned short* pr = P + (long)node*512 + q*4;
  ushort4 vr = *(const ushort4*)(pr);
  ushort4 vz = *(const ushort4*)(pr + 128);
  ushort4 vn = *(const ushort4*)(pr + 256);
  ushort4 vh = *(const ushort4*)(pr + 384);
  float4 hv = *(const float4*)(h + (long)node*H + q*4);
  float srv[4] = {bf2f(vr.x), bf2f(vr.y), bf2f(vr.z), bf2f(vr.w)};
  float szv[4] = {bf2f(vz.x), bf2f(vz.y), bf2f(vz.z), bf2f(vz.w)};
  float snv[4] = {bf2f(vn.x), bf2f(vn.y), bf2f(vn.z), bf2f(vn.w)};
  float shv[4] = {bf2f(vh.x), bf2f(vh.y), bf2f(vh.z), bf2f(vh.w)};
  float hvv[4] = {hv.x, hv.y, hv.z, hv.w};
  float o[4];
  #pragma unroll
  for(int j=0;j<4;++j){
    float r = 1.f/(1.f + __expf(-srv[j]));
    float z = 1.f/(1.f + __expf(-szv[j]));
    float narg = snv[j] + (r - 1.f)*shv[j];
    float n = 2.f/(1.f + __expf(-2.f*narg)) - 1.f;
    o[j] = (1.f - z)*n + z*hvv[j];
  }
  float4 ov = {o[0], o[1], o[2], o[3]};
  *(float4*)(out + (long)node*H + q*4) = ov;
}

extern "C" void kernel_launch(void* const* d_in, const int* in_sizes, int n_in,
                              void* d_out, int out_size, void* d_ws, size_t ws_size,
                              hipStream_t stream){
  const float* x     = (const float*)d_in[0];
  const float* h     = (const float*)d_in[1];
  const int*   src   = (const int*)d_in[2];
  const int*   dst   = (const int*)d_in[3];
  const float* W_msg = (const float*)d_in[4];
  const float* b_msg = (const float*)d_in[5];
  const float* W_ih  = (const float*)d_in[6];
  const float* W_hh  = (const float*)d_in[7];
  const float* b_ih  = (const float*)d_in[8];
  const float* b_hh  = (const float*)d_in[9];
  const int N = in_sizes[0] / H;
  const int E = in_sizes[2];
  float* out = (float*)d_out;

  char* p = (char*)d_ws;
  auto alloc = [&](size_t bytes)->char*{
    char* r = p; p += (bytes + 255) & ~(size_t)255; return r;
  };
  unsigned short* xb    = (unsigned short*)alloc((size_t)N*H*2);
  unsigned short* hb    = (unsigned short*)alloc((size_t)N*H*2);
  unsigned short* Sb    = (unsigned short*)alloc((size_t)N*256*2);
  unsigned short* cb    = (unsigned short*)alloc((size_t)N*H*2);
  unsigned short* P     = (unsigned short*)alloc((size_t)N*512*2);
  unsigned short* Wmsgb = (unsigned short*)alloc(128*256*2);
  unsigned short* Wbig  = (unsigned short*)alloc(512*384*2);
  float*          biasb = (float*)alloc(512*4);
  int*            deg   = (int*)alloc((size_t)N*4);
  int*            rs    = (int*)alloc((size_t)(N+1)*4);
  int*            rc    = (int*)alloc((size_t)N*4);
  int*            ss    = (int*)alloc((size_t)E*4);

  hipMemsetAsync(deg, 0, (size_t)N*4, stream);
  prep_kernel<<<(512*384 + 128*256 + 512 + 255)/256, 256, 0, stream>>>(
      W_msg, W_ih, W_hh, b_ih, b_hh, Wmsgb, Wbig, biasb);
  int nv = N*H/4;
  convert_kernel<<<(2*nv + 255)/256, 256, 0, stream>>>(x, h, xb, hb, nv);
  hist_kernel<<<(E + 255)/256, 256, 0, stream>>>(dst, deg, E);
  int CH = (N + 1023)/1024;
  scan_kernel<<<1, 1024, 0, stream>>>(deg, rs, rc, N, CH);
  fill_kernel<<<(E + 255)/256, 256, 0, stream>>>(src, dst, rc, ss, E);
  agg_kernel<<<(N + 3)/4, 256, 0, stream>>>(xb, hb, rs, ss, Sb, N);

  dim3 g1((N + 127)/128, 1);
  gemm_kernel<256,128,true><<<g1, 256, 0, stream>>>(
      Sb, Sb + 128, Sb, 256, 256, 256, Wmsgb, b_msg, deg, cb, N);
  dim3 g2((N + 127)/128, 4);
  gemm_kernel<384,512,false><<<g2, 256, 0, stream>>>(
      xb, cb, hb, H, H, H, Wbig, biasb, nullptr, P, N);
  gates_kernel<<<(N*32 + 255)/256, 256, 0, stream>>>(P, h, out, N);
}

// Round 2
// 285.008 us; speedup vs baseline: 1.3441x; 1.3441x over previous
//
#include <hip/hip_runtime.h>

#define H 128

typedef __attribute__((ext_vector_type(8))) short s16x8;
typedef __attribute__((ext_vector_type(4))) float f32x4;

__device__ __forceinline__ float bf2f(unsigned short u){
  unsigned x = ((unsigned)u) << 16;
  return __builtin_bit_cast(float, x);
}
__device__ __forceinline__ unsigned short f2bf(float f){
  unsigned u = __builtin_bit_cast(unsigned, f);
  u += 0x7fff + ((u >> 16) & 1);
  return (unsigned short)(u >> 16);
}

// ---- weight prep: W_big [512][384] bf16, W_msg bf16, bias_big f32[512] ----
__global__ void prep_kernel(const float* W_msg, const float* W_ih, const float* W_hh,
                            const float* b_ih, const float* b_hh,
                            unsigned short* Wmsgb, unsigned short* Wbig, float* biasb){
  int i = blockIdx.x*256 + threadIdx.x;
  const int NW = 512*384;
  if(i < NW){
    int r = i / 384, k = i % 384;
    float v;
    if(r < 384) v = (k < 256) ? W_ih[r*256 + k] : W_hh[r*128 + (k-256)];
    else        v = (k < 256) ? 0.f : W_hh[(256 + (r-384))*128 + (k-256)];
    Wbig[i] = f2bf(v);
  } else if(i < NW + 128*256){
    int j = i - NW;
    Wmsgb[j] = f2bf(W_msg[j]);
  } else if(i < NW + 128*256 + 512){
    int r = i - NW - 128*256;
    biasb[r] = (r < 384) ? (b_ih[r] + b_hh[r]) : b_hh[256 + (r-384)];
  }
}

// ---- convert x,h f32 -> bf16 ----
__global__ void convert_kernel(const float* x, const float* h,
                               unsigned short* xb, unsigned short* hb, int nv){
  int i = blockIdx.x*256 + threadIdx.x;
  const float* sp; unsigned short* dp; int j;
  if(i < nv){ sp = x; dp = xb; j = i; }
  else if(i < 2*nv){ sp = h; dp = hb; j = i - nv; }
  else return;
  float4 v = ((const float4*)sp)[j];
  ushort4 o; o.x=f2bf(v.x); o.y=f2bf(v.y); o.z=f2bf(v.z); o.w=f2bf(v.w);
  ((ushort4*)dp)[j] = o;
}

// ---- CSR build ----
__global__ void hist_kernel(const int* dst, int* deg, int E){
  int e = blockIdx.x*256 + threadIdx.x;
  if(e < E) atomicAdd(&deg[dst[e]], 1);
}

// hierarchical scan: A) per-block (2048-chunk) exclusive scan + block sums
__global__ void scanA_kernel(const int* deg, int* rs, int* bsum, int N){
  __shared__ int buf[256];
  int b = blockIdx.x, t = threadIdx.x;
  int base = b*2048 + t*8;
  int v[8]; int s = 0;
  #pragma unroll
  for(int j=0;j<8;++j){ int idx = base+j; v[j] = (idx<N)?deg[idx]:0; s += v[j]; }
  buf[t] = s; __syncthreads();
  #pragma unroll
  for(int off=1; off<256; off<<=1){
    int u = (t>=off)?buf[t-off]:0;
    __syncthreads();
    buf[t] += u;
    __syncthreads();
  }
  int run = buf[t] - s;  // exclusive prefix of thread sums
  #pragma unroll
  for(int j=0;j<8;++j){ int idx = base+j; if(idx<N) rs[idx] = run; run += v[j]; }
  if(t == 255) bsum[b] = buf[255];
}

// B) scan block sums (nb <= 64), write grand total to rsN
__global__ void scanB_kernel(int* bsum, int* rsN, int nb){
  __shared__ int buf[64];
  int t = threadIdx.x;
  int v = (t < nb) ? bsum[t] : 0;
  buf[t] = v; __syncthreads();
  #pragma unroll
  for(int off=1; off<64; off<<=1){
    int u = (t>=off)?buf[t-off]:0;
    __syncthreads();
    buf[t] += u;
    __syncthreads();
  }
  if(t < nb) bsum[t] = buf[t] - v;  // exclusive block offsets
  if(t == 63) *rsN = buf[63];       // grand total
}

// C) add block offsets; duplicate into fill-cursor rc
__global__ void scanC_kernel(int* rs, int* rc, const int* bsum, int N){
  int i = blockIdx.x*256 + threadIdx.x;
  if(i < N){ int v = rs[i] + bsum[i >> 11]; rs[i] = v; rc[i] = v; }
}

__global__ void fill_kernel(const int* src, const int* dst, int* rc, int* ss, int E){
  int e = blockIdx.x*256 + threadIdx.x;
  if(e < E){ int p = atomicAdd(&rc[dst[e]], 1); ss[p] = src[e]; }
}

// ---- aggregation: one wave per node, mean of concat(xb[src], hb[src]) -> Sb bf16 [N][256] ----
__global__ void agg_kernel(const unsigned short* xb, const unsigned short* hb,
                           const int* rs, const int* ss, unsigned short* Sb, int N){
  int wv = threadIdx.x >> 6, lane = threadIdx.x & 63;
  int node = blockIdx.x*4 + wv;
  if(node >= N) return;
  int e0 = rs[node], e1 = rs[node+1];
  const unsigned short* base = (lane < 32) ? xb : hb;
  int co = (lane & 31)*4;
  float a0=0.f, a1=0.f, a2=0.f, a3=0.f;
  for(int e=e0; e<e1; ++e){
    int s = ss[e];  // same address across wave -> broadcast
    ushort4 v = *(const ushort4*)(base + (long)s*H + co);
    a0 += bf2f(v.x); a1 += bf2f(v.y); a2 += bf2f(v.z); a3 += bf2f(v.w);
  }
  float inv = (e1 > e0) ? 1.0f/(float)(e1 - e0) : 0.f;
  ushort4 o; o.x=f2bf(a0*inv); o.y=f2bf(a1*inv); o.z=f2bf(a2*inv); o.w=f2bf(a3*inv);
  *(ushort4*)(Sb + (long)node*256 + lane*4) = o;
}

// ---- NT GEMM: out[M][NC] bf16 = A[M][K] (segments of 128 along K) @ B[NC][K]^T + bias ----
// 128x128 tile, BK=64, 4 waves, 16x16x32 bf16 MFMA, XOR-swizzled LDS.
template<int K, int NC, bool MASK>
__global__ __launch_bounds__(256) void gemm_kernel(
    const unsigned short* A0, const unsigned short* A1, const unsigned short* A2,
    int st0, int st1, int st2,
    const unsigned short* B, const float* bias, const int* deg,
    unsigned short* out, int M){
  __shared__ __align__(16) unsigned short ldsA[128*64];
  __shared__ __align__(16) unsigned short ldsB[128*64];
  int tid = threadIdx.x;
  int lane = tid & 63, wv = tid >> 6;
  int wr = wv >> 1, wc = wv & 1;
  int l15 = lane & 15, l4 = lane >> 4;
  long rowbase = (long)blockIdx.x * 128;
  int colbase = blockIdx.y * 128;

  const f32x4 fz = {0.f, 0.f, 0.f, 0.f};
  f32x4 acc[4][4];
  #pragma unroll
  for(int m=0;m<4;++m)
    #pragma unroll
    for(int n=0;n<4;++n) acc[m][n] = fz;

  for(int kt=0; kt<K/64; ++kt){
    // stage 128x64 A-tile and B-tile: linear global reads, swizzled LDS writes
    #pragma unroll
    for(int it=0; it<4; ++it){
      int slot = it*256 + tid;         // 0..1023
      int row = slot >> 3, c = slot & 7;
      int cw = c ^ (row & 7);
      // A (segmented along K in 128-col pieces)
      int kg = kt*64 + c*8;
      int seg = kg >> 7, kin = kg & 127;
      const unsigned short* ap = (seg==0) ? A0 : ((seg==1) ? A1 : A2);
      int st = (seg==0) ? st0 : ((seg==1) ? st1 : st2);
      long gr = rowbase + row; if(gr > M-1) gr = M-1;
      s16x8 va = *(const s16x8*)(ap + gr*(long)st + kin);
      *(s16x8*)((char*)ldsA + row*128 + cw*16) = va;
      // B: [NC][K] row-major
      s16x8 vb = *(const s16x8*)(B + (long)(colbase + row)*K + kt*64 + c*8);
      *(s16x8*)((char*)ldsB + row*128 + cw*16) = vb;
    }
    __syncthreads();

    s16x8 af[4][2], bfr[4][2];
    #pragma unroll
    for(int m=0;m<4;++m){
      int row = wr*64 + m*16 + l15;
      #pragma unroll
      for(int kk=0;kk<2;++kk){
        int ch = kk*4 + l4;
        af[m][kk] = *(const s16x8*)((char*)ldsA + row*128 + ((ch ^ (row & 7))*16));
      }
    }
    #pragma unroll
    for(int n=0;n<4;++n){
      int row = wc*64 + n*16 + l15;
      #pragma unroll
      for(int kk=0;kk<2;++kk){
        int ch = kk*4 + l4;
        bfr[n][kk] = *(const s16x8*)((char*)ldsB + row*128 + ((ch ^ (row & 7))*16));
      }
    }
    #pragma unroll
    for(int kk=0;kk<2;++kk)
      #pragma unroll
      for(int m=0;m<4;++m)
        #pragma unroll
        for(int n=0;n<4;++n)
          acc[m][n] = __builtin_amdgcn_mfma_f32_16x16x32_bf16(af[m][kk], bfr[n][kk], acc[m][n], 0, 0, 0);
    __syncthreads();
  }

  // epilogue: C/D layout col=lane&15, row=(lane>>4)*4+reg
  float bv[4];
  #pragma unroll
  for(int n=0;n<4;++n) bv[n] = bias[colbase + wc*64 + n*16 + l15];
  #pragma unroll
  for(int m=0;m<4;++m){
    long r0 = rowbase + wr*64 + m*16 + l4*4;
    #pragma unroll
    for(int n=0;n<4;++n){
      int col = colbase + wc*64 + n*16 + l15;
      #pragma unroll
      for(int r=0;r<4;++r){
        long row = r0 + r;
        if(row < M){
          float v = acc[m][n][r] + bv[n];
          if(MASK) v = (deg[row] > 0) ? v : 0.f;
          out[row*(long)NC + col] = f2bf(v);
        }
      }
    }
  }
}

// ---- gates: r,z,n + output ----
__global__ void gates_kernel(const unsigned short* P, const float* h, float* out, int N){
  int gid = blockIdx.x*256 + threadIdx.x;
  int node = gid >> 5, q = gid & 31;
  if(node >= N) return;
  const unsigned short* pr = P + (long)node*512 + q*4;
  ushort4 vr = *(const ushort4*)(pr);
  ushort4 vz = *(const ushort4*)(pr + 128);
  ushort4 vn = *(const ushort4*)(pr + 256);
  ushort4 vh = *(const ushort4*)(pr + 384);
  float4 hv = *(const float4*)(h + (long)node*H + q*4);
  float srv[4] = {bf2f(vr.x), bf2f(vr.y), bf2f(vr.z), bf2f(vr.w)};
  float szv[4] = {bf2f(vz.x), bf2f(vz.y), bf2f(vz.z), bf2f(vz.w)};
  float snv[4] = {bf2f(vn.x), bf2f(vn.y), bf2f(vn.z), bf2f(vn.w)};
  float shv[4] = {bf2f(vh.x), bf2f(vh.y), bf2f(vh.z), bf2f(vh.w)};
  float hvv[4] = {hv.x, hv.y, hv.z, hv.w};
  float o[4];
  #pragma unroll
  for(int j=0;j<4;++j){
    float r = 1.f/(1.f + __expf(-srv[j]));
    float z = 1.f/(1.f + __expf(-szv[j]));
    float narg = snv[j] + (r - 1.f)*shv[j];
    float n = 2.f/(1.f + __expf(-2.f*narg)) - 1.f;
    o[j] = (1.f - z)*n + z*hvv[j];
  }
  float4 ov = {o[0], o[1], o[2], o[3]};
  *(float4*)(out + (long)node*H + q*4) = ov;
}

extern "C" void kernel_launch(void* const* d_in, const int* in_sizes, int n_in,
                              void* d_out, int out_size, void* d_ws, size_t ws_size,
                              hipStream_t stream){
  const float* x     = (const float*)d_in[0];
  const float* h     = (const float*)d_in[1];
  const int*   src   = (const int*)d_in[2];
  const int*   dst   = (const int*)d_in[3];
  const float* W_msg = (const float*)d_in[4];
  const float* b_msg = (const float*)d_in[5];
  const float* W_ih  = (const float*)d_in[6];
  const float* W_hh  = (const float*)d_in[7];
  const float* b_ih  = (const float*)d_in[8];
  const float* b_hh  = (const float*)d_in[9];
  const int N = in_sizes[0] / H;
  const int E = in_sizes[2];
  float* out = (float*)d_out;

  char* p = (char*)d_ws;
  auto alloc = [&](size_t bytes)->char*{
    char* r = p; p += (bytes + 255) & ~(size_t)255; return r;
  };
  unsigned short* xb    = (unsigned short*)alloc((size_t)N*H*2);
  unsigned short* hb    = (unsigned short*)alloc((size_t)N*H*2);
  unsigned short* Sb    = (unsigned short*)alloc((size_t)N*256*2);
  unsigned short* cb    = (unsigned short*)alloc((size_t)N*H*2);
  unsigned short* P     = (unsigned short*)alloc((size_t)N*512*2);
  unsigned short* Wmsgb = (unsigned short*)alloc(128*256*2);
  unsigned short* Wbig  = (unsigned short*)alloc(512*384*2);
  float*          biasb = (float*)alloc(512*4);
  int*            deg   = (int*)alloc((size_t)N*4);
  int*            rs    = (int*)alloc((size_t)(N+1)*4);
  int*            rc    = (int*)alloc((size_t)N*4);
  int*            ss    = (int*)alloc((size_t)E*4);
  int*            bsum  = (int*)alloc(64*4);

  hipMemsetAsync(deg, 0, (size_t)N*4, stream);
  prep_kernel<<<(512*384 + 128*256 + 512 + 255)/256, 256, 0, stream>>>(
      W_msg, W_ih, W_hh, b_ih, b_hh, Wmsgb, Wbig, biasb);
  int nv = N*H/4;
  convert_kernel<<<(2*nv + 255)/256, 256, 0, stream>>>(x, h, xb, hb, nv);
  hist_kernel<<<(E + 255)/256, 256, 0, stream>>>(dst, deg, E);
  int nb = (N + 2047)/2048;
  scanA_kernel<<<nb, 256, 0, stream>>>(deg, rs, bsum, N);
  scanB_kernel<<<1, 64, 0, stream>>>(bsum, rs + N, nb);
  scanC_kernel<<<(N + 255)/256, 256, 0, stream>>>(rs, rc, bsum, N);
  fill_kernel<<<(E + 255)/256, 256, 0, stream>>>(src, dst, rc, ss, E);
  agg_kernel<<<(N + 3)/4, 256, 0, stream>>>(xb, hb, rs, ss, Sb, N);

  dim3 g1((N + 127)/128, 1);
  gemm_kernel<256,128,true><<<g1, 256, 0, stream>>>(
      Sb, Sb + 128, Sb, 256, 256, 256, Wmsgb, b_msg, deg, cb, N);
  dim3 g2((N + 127)/128, 4);
  gemm_kernel<384,512,false><<<g2, 256, 0, stream>>>(
      xb, cb, hb, H, H, H, Wbig, biasb, nullptr, P, N);
  gates_kernel<<<(N*32 + 255)/256, 256, 0, stream>>>(P, h, out, N);
}

// Round 3
// 252.790 us; speedup vs baseline: 1.5154x; 1.1275x over previous
//
#include <hip/hip_runtime.h>

#define H 128

typedef __attribute__((ext_vector_type(8))) short s16x8;
typedef __attribute__((ext_vector_type(4))) float f32x4;

__device__ __forceinline__ float bf2f(unsigned short u){
  unsigned x = ((unsigned)u) << 16;
  return __builtin_bit_cast(float, x);
}
__device__ __forceinline__ unsigned short f2bf(float f){
  unsigned u = __builtin_bit_cast(unsigned, f);
  u += 0x7fff + ((u >> 16) & 1);
  return (unsigned short)(u >> 16);
}

// ---- weight prep: W_big [512][384] bf16, W_msg bf16, bias_big f32[512] ----
__global__ void prep_kernel(const float* W_msg, const float* W_ih, const float* W_hh,
                            const float* b_ih, const float* b_hh,
                            unsigned short* Wmsgb, unsigned short* Wbig, float* biasb){
  int i = blockIdx.x*256 + threadIdx.x;
  const int NW = 512*384;
  if(i < NW){
    int r = i / 384, k = i % 384;
    float v;
    if(r < 384) v = (k < 256) ? W_ih[r*256 + k] : W_hh[r*128 + (k-256)];
    else        v = (k < 256) ? 0.f : W_hh[(256 + (r-384))*128 + (k-256)];
    Wbig[i] = f2bf(v);
  } else if(i < NW + 128*256){
    int j = i - NW;
    Wmsgb[j] = f2bf(W_msg[j]);
  } else if(i < NW + 128*256 + 512){
    int r = i - NW - 128*256;
    biasb[r] = (r < 384) ? (b_ih[r] + b_hh[r]) : b_hh[256 + (r-384)];
  }
}

// ---- convert x,h f32 -> bf16 interleaved xh[N][256] (x: cols 0..127, h: cols 128..255) ----
__global__ void convert_kernel(const float* x, const float* h,
                               unsigned short* xh, int nv){
  int i = blockIdx.x*256 + threadIdx.x;
  const float* sp; int j, add;
  if(i < nv){ sp = x; j = i; add = 0; }
  else if(i < 2*nv){ sp = h; j = i - nv; add = 128; }
  else return;
  float4 v = ((const float4*)sp)[j];
  ushort4 o; o.x=f2bf(v.x); o.y=f2bf(v.y); o.z=f2bf(v.z); o.w=f2bf(v.w);
  int node = j >> 5, col = (j & 31)*4;
  *(ushort4*)(xh + (long)node*256 + add + col) = o;
}

// ---- CSR build ----
__global__ void hist_kernel(const int* dst, int* deg, int E){
  int e = blockIdx.x*256 + threadIdx.x;
  if(e < E) atomicAdd(&deg[dst[e]], 1);
}

// hierarchical scan: A) per-block (2048-chunk) exclusive scan + block sums
__global__ void scanA_kernel(const int* deg, int* rs, int* bsum, int N){
  __shared__ int buf[256];
  int b = blockIdx.x, t = threadIdx.x;
  int base = b*2048 + t*8;
  int v[8]; int s = 0;
  #pragma unroll
  for(int j=0;j<8;++j){ int idx = base+j; v[j] = (idx<N)?deg[idx]:0; s += v[j]; }
  buf[t] = s; __syncthreads();
  #pragma unroll
  for(int off=1; off<256; off<<=1){
    int u = (t>=off)?buf[t-off]:0;
    __syncthreads();
    buf[t] += u;
    __syncthreads();
  }
  int run = buf[t] - s;  // exclusive prefix of thread sums
  #pragma unroll
  for(int j=0;j<8;++j){ int idx = base+j; if(idx<N) rs[idx] = run; run += v[j]; }
  if(t == 255) bsum[b] = buf[255];
}

// B) scan block sums (nb <= 64), write grand total to rsN
__global__ void scanB_kernel(int* bsum, int* rsN, int nb){
  __shared__ int buf[64];
  int t = threadIdx.x;
  int v = (t < nb) ? bsum[t] : 0;
  buf[t] = v; __syncthreads();
  #pragma unroll
  for(int off=1; off<64; off<<=1){
    int u = (t>=off)?buf[t-off]:0;
    __syncthreads();
    buf[t] += u;
    __syncthreads();
  }
  if(t < nb) bsum[t] = buf[t] - v;  // exclusive block offsets
  if(t == 63) *rsN = buf[63];       // grand total
}

// C) add block offsets; duplicate into fill-cursor rc
__global__ void scanC_kernel(int* rs, int* rc, const int* bsum, int N){
  int i = blockIdx.x*256 + threadIdx.x;
  if(i < N){ int v = rs[i] + bsum[i >> 11]; rs[i] = v; rc[i] = v; }
}

__global__ void fill_kernel(const int* src, const int* dst, int* rc, int* ss, int E){
  int e = blockIdx.x*256 + threadIdx.x;
  if(e < E){ int p = atomicAdd(&rc[dst[e]], 1); ss[p] = src[e]; }
}

// ---- aggregation: one wave per node; 2 edges/iteration (half-wave each, 16B/lane),
//      unrolled x2 -> 4 gathers in flight. mean of xh[src] rows -> Sb bf16 [N][256] ----
__global__ void agg_kernel(const unsigned short* xh, const int* rs, const int* ss,
                           unsigned short* Sb, int N){
  int wv = threadIdx.x >> 6, lane = threadIdx.x & 63;
  int node = blockIdx.x*4 + wv;
  if(node >= N) return;
  int e0 = rs[node], e1 = rs[node+1];
  int half = lane >> 5;
  int co = (lane & 31)*8;
  float a[8] = {0.f,0.f,0.f,0.f,0.f,0.f,0.f,0.f};
  int cnt = e1 - e0;
  int pairs = cnt >> 1;
  int i = 0;
  for(; i+1 < pairs; i += 2){
    int ea = e0 + 2*i + half;
    int eb = ea + 2;
    int sa = ss[ea], sb = ss[eb];
    s16x8 va = *(const s16x8*)(xh + (long)sa*256 + co);
    s16x8 vb = *(const s16x8*)(xh + (long)sb*256 + co);
    #pragma unroll
    for(int j=0;j<8;++j) a[j] += bf2f((unsigned short)va[j]);
    #pragma unroll
    for(int j=0;j<8;++j) a[j] += bf2f((unsigned short)vb[j]);
  }
  for(; i < pairs; ++i){
    int ea = e0 + 2*i + half;
    int sa = ss[ea];
    s16x8 va = *(const s16x8*)(xh + (long)sa*256 + co);
    #pragma unroll
    for(int j=0;j<8;++j) a[j] += bf2f((unsigned short)va[j]);
  }
  if((cnt & 1) && half == 0){
    int sa = ss[e1-1];
    s16x8 va = *(const s16x8*)(xh + (long)sa*256 + co);
    #pragma unroll
    for(int j=0;j<8;++j) a[j] += bf2f((unsigned short)va[j]);
  }
  #pragma unroll
  for(int j=0;j<8;++j) a[j] += __shfl_xor(a[j], 32, 64);
  if(half == 0){
    float inv = (cnt > 0) ? 1.0f/(float)cnt : 0.f;
    unsigned short o[8];
    #pragma unroll
    for(int j=0;j<8;++j) o[j] = f2bf(a[j]*inv);
    *(s16x8*)(Sb + (long)node*256 + co) = *(const s16x8*)o;
  }
}

// ---- NT GEMM: out[M][NC] bf16 = A[M][K] (segments of 128 along K) @ B[NC][K]^T + bias ----
// 128x128 tile, BK=64, 4 waves, 16x16x32 bf16 MFMA, XOR-swizzled LDS.
template<int K, int NC, bool MASK>
__global__ __launch_bounds__(256) void gemm_kernel(
    const unsigned short* A0, const unsigned short* A1, const unsigned short* A2,
    int st0, int st1, int st2,
    const unsigned short* B, const float* bias, const int* deg,
    unsigned short* out, int M){
  __shared__ __align__(16) unsigned short ldsA[128*64];
  __shared__ __align__(16) unsigned short ldsB[128*64];
  int tid = threadIdx.x;
  int lane = tid & 63, wv = tid >> 6;
  int wr = wv >> 1, wc = wv & 1;
  int l15 = lane & 15, l4 = lane >> 4;
  long rowbase = (long)blockIdx.x * 128;
  int colbase = blockIdx.y * 128;

  const f32x4 fz = {0.f, 0.f, 0.f, 0.f};
  f32x4 acc[4][4];
  #pragma unroll
  for(int m=0;m<4;++m)
    #pragma unroll
    for(int n=0;n<4;++n) acc[m][n] = fz;

  for(int kt=0; kt<K/64; ++kt){
    // stage 128x64 A-tile and B-tile: linear global reads, swizzled LDS writes
    #pragma unroll
    for(int it=0; it<4; ++it){
      int slot = it*256 + tid;         // 0..1023
      int row = slot >> 3, c = slot & 7;
      int cw = c ^ (row & 7);
      // A (segmented along K in 128-col pieces)
      int kg = kt*64 + c*8;
      int seg = kg >> 7, kin = kg & 127;
      const unsigned short* ap = (seg==0) ? A0 : ((seg==1) ? A1 : A2);
      int st = (seg==0) ? st0 : ((seg==1) ? st1 : st2);
      long gr = rowbase + row; if(gr > M-1) gr = M-1;
      s16x8 va = *(const s16x8*)(ap + gr*(long)st + kin);
      *(s16x8*)((char*)ldsA + row*128 + cw*16) = va;
      // B: [NC][K] row-major
      s16x8 vb = *(const s16x8*)(B + (long)(colbase + row)*K + kt*64 + c*8);
      *(s16x8*)((char*)ldsB + row*128 + cw*16) = vb;
    }
    __syncthreads();

    s16x8 af[4][2], bfr[4][2];
    #pragma unroll
    for(int m=0;m<4;++m){
      int row = wr*64 + m*16 + l15;
      #pragma unroll
      for(int kk=0;kk<2;++kk){
        int ch = kk*4 + l4;
        af[m][kk] = *(const s16x8*)((char*)ldsA + row*128 + ((ch ^ (row & 7))*16));
      }
    }
    #pragma unroll
    for(int n=0;n<4;++n){
      int row = wc*64 + n*16 + l15;
      #pragma unroll
      for(int kk=0;kk<2;++kk){
        int ch = kk*4 + l4;
        bfr[n][kk] = *(const s16x8*)((char*)ldsB + row*128 + ((ch ^ (row & 7))*16));
      }
    }
    #pragma unroll
    for(int kk=0;kk<2;++kk)
      #pragma unroll
      for(int m=0;m<4;++m)
        #pragma unroll
        for(int n=0;n<4;++n)
          acc[m][n] = __builtin_amdgcn_mfma_f32_16x16x32_bf16(af[m][kk], bfr[n][kk], acc[m][n], 0, 0, 0);
    __syncthreads();
  }

  // epilogue: C/D layout col=lane&15, row=(lane>>4)*4+reg
  float bv[4];
  #pragma unroll
  for(int n=0;n<4;++n) bv[n] = bias[colbase + wc*64 + n*16 + l15];
  #pragma unroll
  for(int m=0;m<4;++m){
    long r0 = rowbase + wr*64 + m*16 + l4*4;
    #pragma unroll
    for(int n=0;n<4;++n){
      int col = colbase + wc*64 + n*16 + l15;
      #pragma unroll
      for(int r=0;r<4;++r){
        long row = r0 + r;
        if(row < M){
          float v = acc[m][n][r] + bv[n];
          if(MASK) v = (deg[row] > 0) ? v : 0.f;
          out[row*(long)NC + col] = f2bf(v);
        }
      }
    }
  }
}

// ---- gates: r,z,n + output ----
__global__ void gates_kernel(const unsigned short* P, const float* h, float* out, int N){
  int gid = blockIdx.x*256 + threadIdx.x;
  int node = gid >> 5, q = gid & 31;
  if(node >= N) return;
  const unsigned short* pr = P + (long)node*512 + q*4;
  ushort4 vr = *(const ushort4*)(pr);
  ushort4 vz = *(const ushort4*)(pr + 128);
  ushort4 vn = *(const ushort4*)(pr + 256);
  ushort4 vh = *(const ushort4*)(pr + 384);
  float4 hv = *(const float4*)(h + (long)node*H + q*4);
  float srv[4] = {bf2f(vr.x), bf2f(vr.y), bf2f(vr.z), bf2f(vr.w)};
  float szv[4] = {bf2f(vz.x), bf2f(vz.y), bf2f(vz.z), bf2f(vz.w)};
  float snv[4] = {bf2f(vn.x), bf2f(vn.y), bf2f(vn.z), bf2f(vn.w)};
  float shv[4] = {bf2f(vh.x), bf2f(vh.y), bf2f(vh.z), bf2f(vh.w)};
  float hvv[4] = {hv.x, hv.y, hv.z, hv.w};
  float o[4];
  #pragma unroll
  for(int j=0;j<4;++j){
    float r = 1.f/(1.f + __expf(-srv[j]));
    float z = 1.f/(1.f + __expf(-szv[j]));
    float narg = snv[j] + (r - 1.f)*shv[j];
    float n = 2.f/(1.f + __expf(-2.f*narg)) - 1.f;
    o[j] = (1.f - z)*n + z*hvv[j];
  }
  float4 ov = {o[0], o[1], o[2], o[3]};
  *(float4*)(out + (long)node*H + q*4) = ov;
}

extern "C" void kernel_launch(void* const* d_in, const int* in_sizes, int n_in,
                              void* d_out, int out_size, void* d_ws, size_t ws_size,
                              hipStream_t stream){
  const float* x     = (const float*)d_in[0];
  const float* h     = (const float*)d_in[1];
  const int*   src   = (const int*)d_in[2];
  const int*   dst   = (const int*)d_in[3];
  const float* W_msg = (const float*)d_in[4];
  const float* b_msg = (const float*)d_in[5];
  const float* W_ih  = (const float*)d_in[6];
  const float* W_hh  = (const float*)d_in[7];
  const float* b_ih  = (const float*)d_in[8];
  const float* b_hh  = (const float*)d_in[9];
  const int N = in_sizes[0] / H;
  const int E = in_sizes[2];
  float* out = (float*)d_out;

  char* p = (char*)d_ws;
  auto alloc = [&](size_t bytes)->char*{
    char* r = p; p += (bytes + 255) & ~(size_t)255; return r;
  };
  unsigned short* xh    = (unsigned short*)alloc((size_t)N*256*2);
  unsigned short* Sb    = (unsigned short*)alloc((size_t)N*256*2);
  unsigned short* cb    = (unsigned short*)alloc((size_t)N*H*2);
  unsigned short* P     = (unsigned short*)alloc((size_t)N*512*2);
  unsigned short* Wmsgb = (unsigned short*)alloc(128*256*2);
  unsigned short* Wbig  = (unsigned short*)alloc(512*384*2);
  float*          biasb = (float*)alloc(512*4);
  int*            deg   = (int*)alloc((size_t)N*4);
  int*            rs    = (int*)alloc((size_t)(N+1)*4);
  int*            rc    = (int*)alloc((size_t)N*4);
  int*            ss    = (int*)alloc((size_t)E*4);
  int*            bsum  = (int*)alloc(64*4);

  hipMemsetAsync(deg, 0, (size_t)N*4, stream);
  prep_kernel<<<(512*384 + 128*256 + 512 + 255)/256, 256, 0, stream>>>(
      W_msg, W_ih, W_hh, b_ih, b_hh, Wmsgb, Wbig, biasb);
  int nv = N*H/4;
  convert_kernel<<<(2*nv + 255)/256, 256, 0, stream>>>(x, h, xh, nv);
  hist_kernel<<<(E + 255)/256, 256, 0, stream>>>(dst, deg, E);
  int nb = (N + 2047)/2048;
  scanA_kernel<<<nb, 256, 0, stream>>>(deg, rs, bsum, N);
  scanB_kernel<<<1, 64, 0, stream>>>(bsum, rs + N, nb);
  scanC_kernel<<<(N + 255)/256, 256, 0, stream>>>(rs, rc, bsum, N);
  fill_kernel<<<(E + 255)/256, 256, 0, stream>>>(src, dst, rc, ss, E);
  agg_kernel<<<(N + 3)/4, 256, 0, stream>>>(xh, rs, ss, Sb, N);

  dim3 g1((N + 127)/128, 1);
  gemm_kernel<256,128,true><<<g1, 256, 0, stream>>>(
      Sb, Sb + 128, Sb, 256, 256, 256, Wmsgb, b_msg, deg, cb, N);
  dim3 g2((N + 127)/128, 4);
  gemm_kernel<384,512,false><<<g2, 256, 0, stream>>>(
      xh, cb, xh + 128, 256, 128, 256, Wbig, biasb, nullptr, P, N);
  gates_kernel<<<(N*32 + 255)/256, 256, 0, stream>>>(P, h, out, N);
}